// Round 1
// baseline (597.489 us; speedup 1.0000x reference)
//
#include <hip/hip_runtime.h>
#include <math.h>

// Problem constants (B=16, C=64, H=W=128)
#define NB 16
#define CC 64
#define HH 128
#define WW 128
#define NPIX (NB*CC*HH*WW)       // 16777216
#define WELEM (CC*CC*9)          // 36864

typedef __attribute__((ext_vector_type(8))) short short8_t;

__device__ __forceinline__ int dot4(int a, int b, int c) {
    // v_dot4_i32_i8: 4x int8 MAC per instruction
    return __builtin_amdgcn_sdot4(a, b, c, false);
}

// ---------------- kernel 1: global max|x| ----------------
__global__ __launch_bounds__(256) void k_absmax(const float* __restrict__ x,
                                                unsigned* __restrict__ out) {
    const float4* x4 = (const float4*)x;
    const int n4 = NPIX / 4;
    float m = 0.f;
    for (int j = blockIdx.x * blockDim.x + threadIdx.x; j < n4;
         j += gridDim.x * blockDim.x) {
        float4 v = x4[j];
        m = fmaxf(fmaxf(fabsf(v.x), fabsf(v.y)),
                  fmaxf(fmaxf(fabsf(v.z), fabsf(v.w)), m));
    }
    #pragma unroll
    for (int o = 32; o; o >>= 1) m = fmaxf(m, __shfl_down(m, o, 64));
    if ((threadIdx.x & 63) == 0) atomicMax(out, __float_as_uint(m));
}

// ---------------- kernel 2: DoReFa weight quant ----------------
// out layout: w8[(oc*9 + tap)*64 + ic] = 3*wq in {-3,-1,1,3}
__global__ __launch_bounds__(1024) void k_wquant(const float* __restrict__ w1,
                                                 const float* __restrict__ w2,
                                                 signed char* __restrict__ o1,
                                                 signed char* __restrict__ o2) {
    const float* __restrict__ w = blockIdx.x ? w2 : w1;
    signed char* __restrict__ w8 = blockIdx.x ? o2 : o1;
    __shared__ float red[16];
    int tid = threadIdx.x;
    float m = 0.f;
    for (int i = tid; i < WELEM; i += 1024) m = fmaxf(m, fabsf(tanhf(w[i])));
    #pragma unroll
    for (int o = 32; o; o >>= 1) m = fmaxf(m, __shfl_down(m, o, 64));
    if ((tid & 63) == 0) red[tid >> 6] = m;
    __syncthreads();
    if (tid == 0) {
        float v = red[0];
        #pragma unroll
        for (int i = 1; i < 16; ++i) v = fmaxf(v, red[i]);
        red[0] = v;
    }
    __syncthreads();
    float inv = 1.f / (red[0] + 1e-8f);
    for (int i = tid; i < WELEM; i += 1024) {
        float wt = tanhf(w[i]) * inv;                 // [-1, 1]
        float r  = rintf((wt + 1.f) * 1.5f);          // 0..3, round-half-even
        int oc = i / 576, rem = i % 576, ic = rem / 9, tap = rem % 9;
        w8[(oc * 9 + tap) * 64 + ic] = (signed char)(int)(2.f * r - 3.f);
    }
}

// ---------------- conv kernels ----------------
// PHASE 1: in = quantized x (int8 {-1,0,1}), out = int16 acc + atomicMax(relu(out1))
// PHASE 2: in = binarized relu(conv1) (int8 {0,1}), out = fp32 (res + x)
// Tile: 32x32 output pixels, all 64 oc, one image per block. 256 threads.
// Each thread: 4 tasks of 8oc x 8px register tile, dot4 inner loop.
template <int PHASE>
__global__ __launch_bounds__(256) void k_conv(
    const float* __restrict__ x,          // original input
    const short* __restrict__ accin,      // phase2: conv1 int16 acc
    const signed char* __restrict__ w8,   // [oc][tap][ic] in {-3,-1,1,3}
    const float* __restrict__ bias,       // b1 (phase1) or b2 (phase2)
    const float* __restrict__ b1v,        // phase2: b1 for dequant of acc
    const unsigned* __restrict__ scal,    // [0]=bits(max|x|), [1]=bits(max out1)
    short* __restrict__ accout,           // phase1 output
    float* __restrict__ out,              // phase2 output
    unsigned* __restrict__ s2out)         // phase1 atomic max target
{
    __shared__ signed char sA[34 * 34 * 64];   // 73984 B, swizzled [pix][ic]
    __shared__ signed char sW[64 * 9 * 64];    // 36864 B, [oc][tap][ic]

    const int tid = threadIdx.x;
    const int n   = blockIdx.z;
    const int oy0 = blockIdx.y * 32;
    const int ox0 = blockIdx.x * 32;

    const float s1 = __uint_as_float(scal[0]) + 1e-8f;

    // ---- stage weights (2304 int4 = 36864 B) ----
    {
        const int4* src = (const int4*)w8;
        int4* dst = (int4*)sW;
        #pragma unroll
        for (int j = 0; j < 9; ++j) dst[tid + j * 256] = src[tid + j * 256];
    }

    // ---- stage + quantize input tile (34x34 halo, 64 ch) ----
    int iyv[5], ixv[5];
    #pragma unroll
    for (int k = 0; k < 5; ++k) {
        int p = tid + k * 256;
        iyv[k] = p / 34;
        ixv[k] = p % 34;
    }
    if (PHASE == 1) {
        const float inv_s1 = 1.f / s1;
        for (int ic = 0; ic < CC; ++ic) {
            const float* __restrict__ xc = x + ((size_t)n * CC + ic) * (HH * WW);
            #pragma unroll
            for (int k = 0; k < 5; ++k) {
                int p = tid + k * 256;
                if (p < 1156) {
                    int y  = oy0 - 1 + iyv[k];
                    int xx = ox0 - 1 + ixv[k];
                    signed char q = 0;
                    if (y >= 0 && y < HH && xx >= 0 && xx < WW) {
                        float v = xc[y * WW + xx];
                        q = (signed char)(int)rintf(fminf(fmaxf(v * inv_s1, -1.f), 1.f));
                    }
                    sA[p * 64 + (ic ^ (((p >> 3) & 15) << 2))] = q;
                }
            }
        }
    } else {
        const float s2 = __uint_as_float(scal[1]) + 1e-8f;
        const float inv_s2 = 1.f / s2;
        const float sc1 = s1 * (1.f / 3.f);
        for (int ic = 0; ic < CC; ++ic) {
            const short* __restrict__ ac = accin + ((size_t)n * CC + ic) * (HH * WW);
            float b1c = b1v[ic];
            #pragma unroll
            for (int k = 0; k < 5; ++k) {
                int p = tid + k * 256;
                if (p < 1156) {
                    int y  = oy0 - 1 + iyv[k];
                    int xx = ox0 - 1 + ixv[k];
                    signed char q = 0;
                    if (y >= 0 && y < HH && xx >= 0 && xx < WW) {
                        float v = fmaxf(sc1 * (float)ac[y * WW + xx] + b1c, 0.f);
                        q = (signed char)(int)rintf(fminf(v * inv_s2, 1.f));
                    }
                    sA[p * 64 + (ic ^ (((p >> 3) & 15) << 2))] = q;
                }
            }
        }
    }
    __syncthreads();

    // ---- compute: 4 tasks x (8 oc x 8 px) per thread ----
    float sc;
    if (PHASE == 1) sc = s1 * (1.f / 3.f);
    else            sc = (__uint_as_float(scal[1]) + 1e-8f) * (1.f / 3.f);

    float m2 = 0.f;
    for (int t = 0; t < 4; ++t) {
        int task = t * 256 + tid;
        int ocg = task >> 7;            // 0..7
        int pxg = task & 127;           // 0..127
        int row = pxg >> 2;             // 0..31
        int col = (pxg & 3) << 3;       // 0,8,16,24
        int oc0 = ocg << 3;

        int acc[8][8] = {};
        #pragma unroll
        for (int ky = 0; ky < 3; ++ky) {
            #pragma unroll
            for (int kx = 0; kx < 3; ++kx) {
                const int tap = ky * 3 + kx;
                const int Pbase = (row + ky) * 34 + (col + kx);
                const signed char* wbase = sW + (oc0 * 9 + tap) * 64;
                for (int ic4 = 0; ic4 < 16; ++ic4) {
                    int wv[8], av[8];
                    #pragma unroll
                    for (int o = 0; o < 8; ++o)
                        wv[o] = *(const int*)(wbase + o * 576 + (ic4 << 2));
                    #pragma unroll
                    for (int p = 0; p < 8; ++p) {
                        int P = Pbase + p;
                        av[p] = *(const int*)(sA + P * 64 +
                                              ((ic4 << 2) ^ (((P >> 3) & 15) << 2)));
                    }
                    #pragma unroll
                    for (int o = 0; o < 8; ++o)
                        #pragma unroll
                        for (int p = 0; p < 8; ++p)
                            acc[o][p] = dot4(av[p], wv[o], acc[o][p]);
                }
            }
        }

        size_t base = (((size_t)n * CC + oc0) * HH + (oy0 + row)) * WW + (ox0 + col);
        if (PHASE == 1) {
            #pragma unroll
            for (int o = 0; o < 8; ++o) {
                float bo = bias[oc0 + o];
                short8_t sv;
                #pragma unroll
                for (int p = 0; p < 8; ++p) {
                    sv[p] = (short)acc[o][p];
                    m2 = fmaxf(m2, sc * (float)acc[o][p] + bo);  // relu-max (m2>=0)
                }
                *(short8_t*)(accout + base + (size_t)o * (HH * WW)) = sv;
            }
        } else {
            #pragma unroll
            for (int o = 0; o < 8; ++o) {
                float bo = bias[oc0 + o];
                const float* xr = x + base + (size_t)o * (HH * WW);
                float4 xa = *(const float4*)(xr);
                float4 xb = *(const float4*)(xr + 4);
                float4 r0, r1;
                r0.x = sc * (float)acc[o][0] + bo + xa.x;
                r0.y = sc * (float)acc[o][1] + bo + xa.y;
                r0.z = sc * (float)acc[o][2] + bo + xa.z;
                r0.w = sc * (float)acc[o][3] + bo + xa.w;
                r1.x = sc * (float)acc[o][4] + bo + xb.x;
                r1.y = sc * (float)acc[o][5] + bo + xb.y;
                r1.z = sc * (float)acc[o][6] + bo + xb.z;
                r1.w = sc * (float)acc[o][7] + bo + xb.w;
                float* op = out + base + (size_t)o * (HH * WW);
                *(float4*)(op)     = r0;
                *(float4*)(op + 4) = r1;
            }
        }
    }

    if (PHASE == 1) {
        #pragma unroll
        for (int o = 32; o; o >>= 1) m2 = fmaxf(m2, __shfl_down(m2, o, 64));
        if ((tid & 63) == 0) atomicMax(s2out, __float_as_uint(m2));
    }
}

extern "C" void kernel_launch(void* const* d_in, const int* in_sizes, int n_in,
                              void* d_out, int out_size, void* d_ws, size_t ws_size,
                              hipStream_t stream) {
    const float* x  = (const float*)d_in[0];
    const float* w1 = (const float*)d_in[1];
    const float* b1 = (const float*)d_in[2];
    const float* w2 = (const float*)d_in[3];
    const float* b2 = (const float*)d_in[4];
    float* out = (float*)d_out;

    // ws layout
    unsigned*    scal  = (unsigned*)d_ws;                       // [0]=s1 raw, [1]=s2 raw
    signed char* w8_1  = (signed char*)d_ws + 256;              // 36864 B
    signed char* w8_2  = w8_1 + WELEM;                          // 36864 B
    short*       acc16 = (short*)((char*)d_ws + 131072);        // 33.5 MB

    hipMemsetAsync(d_ws, 0, 16, stream);
    k_absmax<<<2048, 256, 0, stream>>>(x, scal);
    k_wquant<<<2, 1024, 0, stream>>>(w1, w2, w8_1, w8_2);

    dim3 grid(4, 4, 16);
    k_conv<1><<<grid, 256, 0, stream>>>(x, nullptr, w8_1, b1, nullptr, scal,
                                        acc16, nullptr, scal + 1);
    k_conv<2><<<grid, 256, 0, stream>>>(x, acc16, w8_2, b2, b1, scal,
                                        nullptr, out, nullptr);
}

// Round 2
// 384.777 us; speedup vs baseline: 1.5528x; 1.5528x over previous
//
#include <hip/hip_runtime.h>
#include <math.h>

// Problem constants (B=16, C=64, H=W=128)
#define NB 16
#define CC 64
#define HH 128
#define WW 128
#define NPIX (NB*CC*HH*WW)       // 16777216
#define WELEM (CC*CC*9)          // 36864

// LDS activation tile geometry: 34x34 halo pixels, stored with
// row pitch 35 pixels and pixel pitch 68 bytes (17 dwords, odd) so that
// bank = (19*r + 17*c + ic4) % 32 covers all 32 banks across a wave's rows.
#define TPITCH 35
#define PXB 68

typedef __attribute__((ext_vector_type(8))) short short8_t;

__device__ __forceinline__ int dot4(int a, int b, int c) {
    return __builtin_amdgcn_sdot4(a, b, c, false);
}

// ---------------- kernel 1: fused global max|x| + DoReFa weight quant ----------------
// blocks 0..2047: absmax(x) -> scal[0];  blocks 2048/2049: quantize w1/w2
__global__ __launch_bounds__(256) void k_reduce(const float* __restrict__ x,
                                                const float* __restrict__ w1,
                                                const float* __restrict__ w2,
                                                unsigned* __restrict__ scal,
                                                signed char* __restrict__ o1,
                                                signed char* __restrict__ o2) {
    const int tid = threadIdx.x;
    if (blockIdx.x < 2048) {
        const float4* x4 = (const float4*)x;
        const int n4 = NPIX / 4;
        float m = 0.f;
        for (int j = blockIdx.x * 256 + tid; j < n4; j += 2048 * 256) {
            float4 v = x4[j];
            m = fmaxf(fmaxf(fabsf(v.x), fabsf(v.y)),
                      fmaxf(fmaxf(fabsf(v.z), fabsf(v.w)), m));
        }
        #pragma unroll
        for (int o = 32; o; o >>= 1) m = fmaxf(m, __shfl_down(m, o, 64));
        if ((tid & 63) == 0) atomicMax(scal, __float_as_uint(m));
    } else {
        const float* __restrict__ w = (blockIdx.x == 2049) ? w2 : w1;
        signed char* __restrict__ w8 = (blockIdx.x == 2049) ? o2 : o1;
        __shared__ float red[4];
        float m = 0.f;
        for (int i = tid; i < WELEM; i += 256) m = fmaxf(m, fabsf(tanhf(w[i])));
        #pragma unroll
        for (int o = 32; o; o >>= 1) m = fmaxf(m, __shfl_down(m, o, 64));
        if ((tid & 63) == 0) red[tid >> 6] = m;
        __syncthreads();
        float inv = 1.f / (fmaxf(fmaxf(red[0], red[1]), fmaxf(red[2], red[3])) + 1e-8f);
        for (int i = tid; i < WELEM; i += 256) {
            float wt = tanhf(w[i]) * inv;                 // [-1, 1]
            float r  = rintf((wt + 1.f) * 1.5f);          // 0..3 (round-half-even)
            int oc = i / 576, rem = i % 576, ic = rem / 9, tap = rem % 9;
            w8[(oc * 9 + tap) * 64 + ic] = (signed char)(int)(2.f * r - 3.f);
        }
    }
}

// ---------------- conv kernels ----------------
// PHASE 1: in = quantized x (int8 {-1,0,1}) -> int16 acc + atomicMax(relu max)
// PHASE 2: in = binarized relu(conv1) (int8 {0,1}) -> fp32 out = res + x
// Tile: 32x32 output pixels, all 64 oc, one image per block. 512 threads.
// Each thread computes an 8oc x 16px register tile (one task).
template <int PHASE>
__global__ __launch_bounds__(512, 2) void k_conv(
    const float* __restrict__ x,          // original input
    const short* __restrict__ accin,      // phase2: conv1 int16 acc
    const signed char* __restrict__ w8,   // [oc][tap][ic] in {-3,-1,1,3}
    const float* __restrict__ bias,       // b1 (phase1) or b2 (phase2)
    const float* __restrict__ b1v,        // phase2: b1 for dequant of acc
    const unsigned* __restrict__ scal,    // [0]=bits(max|x|), [1]=bits(max relu)
    short* __restrict__ accout,           // phase1 output
    float* __restrict__ out,              // phase2 output
    unsigned* __restrict__ s2out)         // phase1 atomic max target
{
    // 34x34 pixels, pitch-35 rows, 68 B per pixel -> 1189*68 = 80852 B
    __shared__ signed char sA[(33 * TPITCH + 33 + 1) * PXB] __attribute__((aligned(16)));
    __shared__ signed char sW[WELEM] __attribute__((aligned(16)));

    const int tid = threadIdx.x;
    const int n   = blockIdx.z;
    const int oy0 = blockIdx.y * 32;
    const int ox0 = blockIdx.x * 32;

    const float s1 = __uint_as_float(scal[0]) + 1e-8f;

    // ---- stage weights (2304 int4 = 36864 B) ----
    {
        const int4* src = (const int4*)w8;
        int4* dst = (int4*)sW;
        #pragma unroll
        for (int j = 0; j < 4; ++j) dst[tid + j * 512] = src[tid + j * 512];
        if (tid < 256) dst[tid + 2048] = src[tid + 2048];
    }

    // ---- stage + quantize input tile (34x34 halo, 64 ch, packed 4 ic/dword) ----
    const float inv_s1 = 1.f / s1;
    float sc1_, inv_s2_;
    if (PHASE == 2) {
        float s2 = __uint_as_float(scal[1]) + 1e-8f;
        inv_s2_ = 1.f / s2;
        sc1_ = s1 * (1.f / 3.f);
    }
    #pragma unroll
    for (int k = 0; k < 3; ++k) {
        int p = tid + k * 512;
        if (p < 34 * 34) {
            int r = p / 34, c = p % 34;
            int y  = oy0 - 1 + r;
            int xx = ox0 - 1 + c;
            signed char* dst = sA + (r * TPITCH + c) * PXB;
            if (y >= 0 && y < HH && xx >= 0 && xx < WW) {
                if (PHASE == 1) {
                    const float* __restrict__ xp =
                        x + (size_t)n * (CC * HH * WW) + y * WW + xx;
                    for (int icg = 0; icg < 16; ++icg) {
                        unsigned pack = 0;
                        #pragma unroll
                        for (int j = 0; j < 4; ++j) {
                            float v = xp[(size_t)(icg * 4 + j) * (HH * WW)];
                            int q = (int)rintf(fminf(fmaxf(v * inv_s1, -1.f), 1.f));
                            pack |= (unsigned)(q & 0xff) << (8 * j);
                        }
                        *(unsigned*)(dst + icg * 4) = pack;
                    }
                } else {
                    const short* __restrict__ ap =
                        accin + (size_t)n * (CC * HH * WW) + y * WW + xx;
                    for (int icg = 0; icg < 16; ++icg) {
                        unsigned pack = 0;
                        #pragma unroll
                        for (int j = 0; j < 4; ++j) {
                            int ic = icg * 4 + j;
                            float v = fmaxf(sc1_ * (float)ap[(size_t)ic * (HH * WW)]
                                            + b1v[ic], 0.f);
                            int q = (int)rintf(fminf(v * inv_s2_, 1.f));
                            pack |= (unsigned)(q & 0xff) << (8 * j);
                        }
                        *(unsigned*)(dst + icg * 4) = pack;
                    }
                }
            } else {
                #pragma unroll
                for (int icg = 0; icg < 16; ++icg) *(unsigned*)(dst + icg * 4) = 0;
            }
        }
    }
    __syncthreads();

    // ---- compute: one 8oc x 16px tile per thread ----
    const int row = (tid & 63) >> 1;        // 0..31
    const int col = (tid & 1) << 4;         // 0 or 16
    const int oc0 = (tid >> 6) << 3;        // wave-uniform -> w reads broadcast

    int acc[8][16] = {};
    #pragma unroll 1
    for (int ic4 = 0; ic4 < 16; ++ic4) {
        #pragma unroll
        for (int ky = 0; ky < 3; ++ky) {
            int arow[18];
            const signed char* abase = sA + ((row + ky) * TPITCH + col) * PXB + ic4 * 4;
            #pragma unroll
            for (int j = 0; j < 18; ++j)
                arow[j] = *(const int*)(abase + j * PXB);
            #pragma unroll
            for (int kx = 0; kx < 3; ++kx) {
                const signed char* wbase = sW + (oc0 * 9 + ky * 3 + kx) * 64 + ic4 * 4;
                int wv[8];
                #pragma unroll
                for (int o = 0; o < 8; ++o) wv[o] = *(const int*)(wbase + o * 576);
                #pragma unroll
                for (int o = 0; o < 8; ++o)
                    #pragma unroll
                    for (int p = 0; p < 16; ++p)
                        acc[o][p] = dot4(arow[kx + p], wv[o], acc[o][p]);
            }
        }
    }

    // ---- epilogue ----
    float sc;
    if (PHASE == 1) sc = s1 * (1.f / 3.f);
    else            sc = (__uint_as_float(scal[1]) + 1e-8f) * (1.f / 3.f);

    size_t base = (((size_t)n * CC + oc0) * HH + (oy0 + row)) * WW + (ox0 + col);
    if (PHASE == 1) {
        float m2 = 0.f;
        #pragma unroll
        for (int o = 0; o < 8; ++o) {
            float bo = bias[oc0 + o];
            short8_t sv0, sv1;
            #pragma unroll
            for (int p = 0; p < 8; ++p) {
                sv0[p] = (short)acc[o][p];
                sv1[p] = (short)acc[o][p + 8];
                m2 = fmaxf(m2, sc * (float)acc[o][p] + bo);
                m2 = fmaxf(m2, sc * (float)acc[o][p + 8] + bo);
            }
            short* op = accout + base + (size_t)o * (HH * WW);
            *(short8_t*)(op)     = sv0;
            *(short8_t*)(op + 8) = sv1;
        }
        #pragma unroll
        for (int o = 32; o; o >>= 1) m2 = fmaxf(m2, __shfl_down(m2, o, 64));
        if ((tid & 63) == 0) atomicMax(s2out, __float_as_uint(m2));
    } else {
        #pragma unroll
        for (int o = 0; o < 8; ++o) {
            float bo = bias[oc0 + o];
            const float* xr = x + base + (size_t)o * (HH * WW);
            float* op = out + base + (size_t)o * (HH * WW);
            #pragma unroll
            for (int q = 0; q < 4; ++q) {
                float4 xa = *(const float4*)(xr + q * 4);
                float4 r;
                r.x = sc * (float)acc[o][q * 4 + 0] + bo + xa.x;
                r.y = sc * (float)acc[o][q * 4 + 1] + bo + xa.y;
                r.z = sc * (float)acc[o][q * 4 + 2] + bo + xa.z;
                r.w = sc * (float)acc[o][q * 4 + 3] + bo + xa.w;
                *(float4*)(op + q * 4) = r;
            }
        }
    }
}

extern "C" void kernel_launch(void* const* d_in, const int* in_sizes, int n_in,
                              void* d_out, int out_size, void* d_ws, size_t ws_size,
                              hipStream_t stream) {
    const float* x  = (const float*)d_in[0];
    const float* w1 = (const float*)d_in[1];
    const float* b1 = (const float*)d_in[2];
    const float* w2 = (const float*)d_in[3];
    const float* b2 = (const float*)d_in[4];
    float* out = (float*)d_out;

    // ws layout
    unsigned*    scal  = (unsigned*)d_ws;                       // [0]=s1 raw, [1]=s2 raw
    signed char* w8_1  = (signed char*)d_ws + 256;              // 36864 B
    signed char* w8_2  = w8_1 + WELEM;                          // 36864 B
    short*       acc16 = (short*)((char*)d_ws + 131072);        // 33.5 MB

    hipMemsetAsync(d_ws, 0, 16, stream);
    k_reduce<<<2050, 256, 0, stream>>>(x, w1, w2, scal, w8_1, w8_2);

    dim3 grid(4, 4, 16);
    k_conv<1><<<grid, 512, 0, stream>>>(x, nullptr, w8_1, b1, nullptr, scal,
                                        acc16, nullptr, scal + 1);
    k_conv<2><<<grid, 512, 0, stream>>>(x, acc16, w8_2, b2, b1, scal,
                                        nullptr, out, nullptr);
}

// Round 3
// 263.969 us; speedup vs baseline: 2.2635x; 1.4577x over previous
//
#include <hip/hip_runtime.h>
#include <math.h>

// Problem constants (B=16, C=64, H=W=128)
#define NB 16
#define CC 64
#define HH 128
#define WW 128
#define NPIX (NB*CC*HH*WW)       // 16777216
#define WELEM (CC*CC*9)          // 36864

// Plane-major LDS activation tile: 16 planes (ic4), each 34 rows x pitch-36 dwords.
// Row stride 36 dwords (16B-aligned, start banks 4r mod 32 -> uniform over banks).
#define ROWP 36
#define APLN (34 * ROWP)         // 1224 dwords per plane

typedef __attribute__((ext_vector_type(8))) short short8_t;

__device__ __forceinline__ int dot4(int a, int b, int c) {
    return __builtin_amdgcn_sdot4(a, b, c, false);
}

// ---------------- kernel 1: fused global max|x| + DoReFa weight quant ----------------
// blocks 0..255: absmax(x) -> scal[0] (ONE atomic per block)
// blocks 256/257: quantize w1/w2 into [tap][ic4][oc][4ic] layout
__global__ __launch_bounds__(1024) void k_reduce(const float* __restrict__ x,
                                                 const float* __restrict__ w1,
                                                 const float* __restrict__ w2,
                                                 unsigned* __restrict__ scal,
                                                 signed char* __restrict__ o1,
                                                 signed char* __restrict__ o2) {
    __shared__ float red[16];
    const int tid = threadIdx.x;
    if (blockIdx.x < 256) {
        const float4* x4 = (const float4*)x;
        const int n4 = NPIX / 4;             // 4194304
        float m = 0.f;
        for (int j = blockIdx.x * 1024 + tid; j < n4; j += 256 * 1024) {  // 16 iters
            float4 v = x4[j];
            m = fmaxf(fmaxf(fabsf(v.x), fabsf(v.y)),
                      fmaxf(fmaxf(fabsf(v.z), fabsf(v.w)), m));
        }
        #pragma unroll
        for (int o = 32; o; o >>= 1) m = fmaxf(m, __shfl_down(m, o, 64));
        if ((tid & 63) == 0) red[tid >> 6] = m;
        __syncthreads();
        if (tid == 0) {
            float v = red[0];
            #pragma unroll
            for (int i = 1; i < 16; ++i) v = fmaxf(v, red[i]);
            atomicMax(scal, __float_as_uint(v));   // 256 atomics total
        }
    } else {
        const float* __restrict__ w = (blockIdx.x == 257) ? w2 : w1;
        signed char* __restrict__ w8 = (blockIdx.x == 257) ? o2 : o1;
        float m = 0.f;
        for (int i = tid; i < WELEM; i += 1024) m = fmaxf(m, fabsf(tanhf(w[i])));
        #pragma unroll
        for (int o = 32; o; o >>= 1) m = fmaxf(m, __shfl_down(m, o, 64));
        if ((tid & 63) == 0) red[tid >> 6] = m;
        __syncthreads();
        float mx = 0.f;
        #pragma unroll
        for (int i = 0; i < 16; ++i) mx = fmaxf(mx, red[i]);
        float inv = 1.f / (mx + 1e-8f);
        for (int i = tid; i < WELEM; i += 1024) {
            float wt = tanhf(w[i]) * inv;                 // [-1, 1]
            float r  = rintf((wt + 1.f) * 1.5f);          // 0..3 (round-half-even)
            int oc = i / 576, rem = i % 576, ic = rem / 9, tap = rem % 9;
            w8[(tap * 16 + (ic >> 2)) * 256 + oc * 4 + (ic & 3)] =
                (signed char)(int)(2.f * r - 3.f);
        }
    }
}

// ---------------- conv kernels ----------------
// PHASE 1: in = quantized x (int8 {-1,0,1}) -> int16 acc + per-block max(relu)
// PHASE 2: in = binarized relu(conv1) (int8 {0,1}) -> fp32 out = res + x
// Tile: 32x32 output pixels, all 64 oc, one image per block. 512 threads.
// Each thread computes an 8oc x 16px register tile.
template <int PHASE>
__global__ __launch_bounds__(512, 2) void k_conv(
    const float* __restrict__ x,          // original input
    const short* __restrict__ accin,      // phase2: conv1 int16 acc
    const signed char* __restrict__ w8,   // [tap][ic4][oc][4ic] in {-3,-1,1,3}
    const float* __restrict__ bias,       // b1 (phase1) or b2 (phase2)
    const float* __restrict__ b1v,        // phase2: b1 for dequant of acc
    const unsigned* __restrict__ scal,    // [0]=bits(max|x|), [1]=bits(max relu)
    short* __restrict__ accout,           // phase1 output
    float* __restrict__ out,              // phase2 output
    unsigned* __restrict__ s2out)         // phase1 atomic max target
{
    __shared__ int sA[16 * APLN];   // 78336 B, plane-major packed activations
    __shared__ int sW[WELEM / 4];   // 36864 B, [tap][ic4][oc] dwords
    __shared__ float redm[8];

    const int tid = threadIdx.x;
    const int n   = blockIdx.z;
    const int oy0 = blockIdx.y * 32;
    const int ox0 = blockIdx.x * 32;

    const float s1 = __uint_as_float(scal[0]) + 1e-8f;

    // ---- stage weights (2304 int4 = 36864 B) ----
    {
        const int4* src = (const int4*)w8;
        int4* dst = (int4*)sW;
        #pragma unroll
        for (int j = 0; j < 4; ++j) dst[tid + j * 512] = src[tid + j * 512];
        if (tid < 256) dst[tid + 2048] = src[tid + 2048];
    }

    // ---- stage + quantize input tile (34x34 halo, 64 ch, packed 4 ic/dword) ----
    const float inv_s1 = 1.f / s1;
    float sc1_, half_s2_;
    if (PHASE == 2) {
        float s2 = __uint_as_float(scal[1]) + 1e-8f;
        half_s2_ = 0.5f * s2;
        sc1_ = s1 * (1.f / 3.f);
    }
    #pragma unroll
    for (int k = 0; k < 3; ++k) {
        int p = tid + k * 512;
        if (p < 34 * 34) {
            int r = p / 34, c = p % 34;
            int y  = oy0 - 1 + r;
            int xx = ox0 - 1 + c;
            int* dst = sA + r * ROWP + c;
            if (y >= 0 && y < HH && xx >= 0 && xx < WW) {
                if (PHASE == 1) {
                    const float* __restrict__ xp =
                        x + (size_t)n * (CC * HH * WW) + y * WW + xx;
                    for (int icg = 0; icg < 16; ++icg) {
                        unsigned pack = 0;
                        #pragma unroll
                        for (int j = 0; j < 4; ++j) {
                            float v = xp[(size_t)(icg * 4 + j) * (HH * WW)];
                            int q = (int)rintf(fminf(fmaxf(v * inv_s1, -1.f), 1.f));
                            pack |= (unsigned)(q & 0xff) << (8 * j);
                        }
                        dst[icg * APLN] = (int)pack;
                    }
                } else {
                    const short* __restrict__ ap =
                        accin + (size_t)n * (CC * HH * WW) + y * WW + xx;
                    for (int icg = 0; icg < 16; ++icg) {
                        unsigned pack = 0;
                        #pragma unroll
                        for (int j = 0; j < 4; ++j) {
                            int ic = icg * 4 + j;
                            float v = sc1_ * (float)ap[(size_t)ic * (HH * WW)] + b1v[ic];
                            if (v >= half_s2_) pack |= 1u << (8 * j);
                        }
                        dst[icg * APLN] = (int)pack;
                    }
                }
            } else {
                #pragma unroll
                for (int icg = 0; icg < 16; ++icg) dst[icg * APLN] = 0;
            }
        }
    }
    __syncthreads();

    // ---- compute: one 8oc x 16px tile per thread ----
    const int row = (tid & 63) >> 1;        // 0..31
    const int col = (tid & 1) << 4;         // 0 or 16
    const int oc0 = (tid >> 6) << 3;        // wave-uniform -> w reads broadcast

    int acc[8][16] = {};
    #pragma unroll 1
    for (int ic4 = 0; ic4 < 16; ++ic4) {
        #pragma unroll
        for (int ky = 0; ky < 3; ++ky) {
            const int* abase = sA + ic4 * APLN + (row + ky) * ROWP + col;
            int arow[18];
            {
                int4 t0 = *(const int4*)(abase);
                int4 t1 = *(const int4*)(abase + 4);
                int4 t2 = *(const int4*)(abase + 8);
                int4 t3 = *(const int4*)(abase + 12);
                int2 t4 = *(const int2*)(abase + 16);
                arow[0]=t0.x;  arow[1]=t0.y;  arow[2]=t0.z;  arow[3]=t0.w;
                arow[4]=t1.x;  arow[5]=t1.y;  arow[6]=t1.z;  arow[7]=t1.w;
                arow[8]=t2.x;  arow[9]=t2.y;  arow[10]=t2.z; arow[11]=t2.w;
                arow[12]=t3.x; arow[13]=t3.y; arow[14]=t3.z; arow[15]=t3.w;
                arow[16]=t4.x; arow[17]=t4.y;
            }
            #pragma unroll
            for (int kx = 0; kx < 3; ++kx) {
                const int* wbase = sW + ((ky * 3 + kx) * 16 + ic4) * 64 + oc0;
                int4 wA = *(const int4*)(wbase);
                int4 wB = *(const int4*)(wbase + 4);
                int wv[8] = {wA.x, wA.y, wA.z, wA.w, wB.x, wB.y, wB.z, wB.w};
                #pragma unroll
                for (int o = 0; o < 8; ++o)
                    #pragma unroll
                    for (int p = 0; p < 16; ++p)
                        acc[o][p] = dot4(arow[kx + p], wv[o], acc[o][p]);
            }
        }
    }

    // ---- epilogue ----
    float sc;
    if (PHASE == 1) sc = s1 * (1.f / 3.f);
    else            sc = (__uint_as_float(scal[1]) + 1e-8f) * (1.f / 3.f);

    size_t base = (((size_t)n * CC + oc0) * HH + (oy0 + row)) * WW + (ox0 + col);
    if (PHASE == 1) {
        float m2 = 0.f;
        #pragma unroll
        for (int o = 0; o < 8; ++o) {
            float bo = bias[oc0 + o];
            short8_t sv0, sv1;
            #pragma unroll
            for (int p = 0; p < 8; ++p) {
                sv0[p] = (short)acc[o][p];
                sv1[p] = (short)acc[o][p + 8];
                m2 = fmaxf(m2, sc * (float)acc[o][p] + bo);
                m2 = fmaxf(m2, sc * (float)acc[o][p + 8] + bo);
            }
            short* op = accout + base + (size_t)o * (HH * WW);
            *(short8_t*)(op)     = sv0;
            *(short8_t*)(op + 8) = sv1;
        }
        #pragma unroll
        for (int o = 32; o; o >>= 1) m2 = fmaxf(m2, __shfl_down(m2, o, 64));
        if ((tid & 63) == 0) redm[tid >> 6] = m2;
        __syncthreads();
        if (tid == 0) {
            float v = redm[0];
            #pragma unroll
            for (int i = 1; i < 8; ++i) v = fmaxf(v, redm[i]);
            atomicMax(s2out, __float_as_uint(v));   // ONE atomic per block
        }
    } else {
        #pragma unroll
        for (int o = 0; o < 8; ++o) {
            float bo = bias[oc0 + o];
            const float* xr = x + base + (size_t)o * (HH * WW);
            float* op = out + base + (size_t)o * (HH * WW);
            #pragma unroll
            for (int q = 0; q < 4; ++q) {
                float4 xa = *(const float4*)(xr + q * 4);
                float4 r;
                r.x = sc * (float)acc[o][q * 4 + 0] + bo + xa.x;
                r.y = sc * (float)acc[o][q * 4 + 1] + bo + xa.y;
                r.z = sc * (float)acc[o][q * 4 + 2] + bo + xa.z;
                r.w = sc * (float)acc[o][q * 4 + 3] + bo + xa.w;
                *(float4*)(op + q * 4) = r;
            }
        }
    }
}

extern "C" void kernel_launch(void* const* d_in, const int* in_sizes, int n_in,
                              void* d_out, int out_size, void* d_ws, size_t ws_size,
                              hipStream_t stream) {
    const float* x  = (const float*)d_in[0];
    const float* w1 = (const float*)d_in[1];
    const float* b1 = (const float*)d_in[2];
    const float* w2 = (const float*)d_in[3];
    const float* b2 = (const float*)d_in[4];
    float* out = (float*)d_out;

    // ws layout
    unsigned*    scal  = (unsigned*)d_ws;                       // [0]=s1 raw, [1]=s2 raw
    signed char* w8_1  = (signed char*)d_ws + 256;              // 36864 B
    signed char* w8_2  = w8_1 + WELEM;                          // 36864 B
    short*       acc16 = (short*)((char*)d_ws + 131072);        // 33.5 MB

    hipMemsetAsync(d_ws, 0, 16, stream);
    k_reduce<<<258, 1024, 0, stream>>>(x, w1, w2, scal, w8_1, w8_2);

    dim3 grid(4, 4, 16);
    k_conv<1><<<grid, 512, 0, stream>>>(x, nullptr, w8_1, b1, nullptr, scal,
                                        acc16, nullptr, scal + 1);
    k_conv<2><<<grid, 512, 0, stream>>>(x, acc16, w8_2, b2, b1, scal,
                                        nullptr, out, nullptr);
}

// Round 4
// 144.768 us; speedup vs baseline: 4.1272x; 1.8234x over previous
//
#include <hip/hip_runtime.h>
#include <math.h>

// Problem constants (B=16, C=64, H=W=128)
#define NB 16
#define CC 64
#define HH 128
#define WW 128
#define NPIX (NB*CC*HH*WW)       // 16777216
#define WELEM (CC*CC*9)          // 36864

// conv tiling: 16 rows x 32 cols output per block, all 64 oc. halo 18x34.
#define TR 16
#define TC 32
#define HR 18
#define HC 34
#define HPX (HR*HC)              // 612 halo pixels

typedef __attribute__((ext_vector_type(4))) int int32x4;

// LDS activation layout: [pix][64B of ic], with the 4 16B-chunks XOR-swizzled
// by (pix>>1)&3 so a wave's b128 fragment reads (16 consecutive pix x 4 chunks)
// spread over all 32 banks.
__device__ __forceinline__ int lds_a(int pix, int q) {
    return pix * 64 + ((q ^ ((pix >> 1) & 3)) << 4);
}

// ---------------- kernel 1: fused global max|x| + DoReFa weight quant ----------------
// blocks 0..255: absmax(x) -> scal[0] (ONE atomic per block)
// blocks 256/257: quantize w1/w2 into MFMA A-fragment order [m][tap][lane][16B]
__global__ __launch_bounds__(1024) void k_reduce(const float* __restrict__ x,
                                                 const float* __restrict__ w1,
                                                 const float* __restrict__ w2,
                                                 unsigned* __restrict__ scal,
                                                 signed char* __restrict__ o1,
                                                 signed char* __restrict__ o2) {
    __shared__ float red[16];
    const int tid = threadIdx.x;
    if (blockIdx.x < 256) {
        const float4* x4 = (const float4*)x;
        const int n4 = NPIX / 4;
        float m = 0.f;
        for (int j = blockIdx.x * 1024 + tid; j < n4; j += 256 * 1024) {
            float4 v = x4[j];
            m = fmaxf(fmaxf(fabsf(v.x), fabsf(v.y)),
                      fmaxf(fmaxf(fabsf(v.z), fabsf(v.w)), m));
        }
        #pragma unroll
        for (int o = 32; o; o >>= 1) m = fmaxf(m, __shfl_down(m, o, 64));
        if ((tid & 63) == 0) red[tid >> 6] = m;
        __syncthreads();
        if (tid == 0) {
            float v = red[0];
            #pragma unroll
            for (int i = 1; i < 16; ++i) v = fmaxf(v, red[i]);
            atomicMax(scal, __float_as_uint(v));
        }
    } else {
        const float* __restrict__ w = (blockIdx.x == 257) ? w2 : w1;
        signed char* __restrict__ w8 = (blockIdx.x == 257) ? o2 : o1;
        float m = 0.f;
        for (int i = tid; i < WELEM; i += 1024) m = fmaxf(m, fabsf(tanhf(w[i])));
        #pragma unroll
        for (int o = 32; o; o >>= 1) m = fmaxf(m, __shfl_down(m, o, 64));
        if ((tid & 63) == 0) red[tid >> 6] = m;
        __syncthreads();
        float mx = 0.f;
        #pragma unroll
        for (int i = 0; i < 16; ++i) mx = fmaxf(mx, red[i]);
        float inv = 1.f / (mx + 1e-8f);
        for (int i = tid; i < WELEM; i += 1024) {
            float wt = tanhf(w[i]) * inv;                 // [-1, 1]
            float r  = rintf((wt + 1.f) * 1.5f);          // 0..3 (round-half-even)
            int oc = i / 576, rem = i % 576, ic = rem / 9, tap = rem % 9;
            // A-fragment: lane = (oc&15) | ((ic>>4)<<4); k-byte = ic&15
            int lane2 = (oc & 15) | ((ic >> 4) << 4);
            w8[(((oc >> 4) * 9 + tap) * 64 + lane2) * 16 + (ic & 15)] =
                (signed char)(int)(2.f * r - 3.f);
        }
    }
}

// ---------------- conv kernels (im2col GEMM on v_mfma_i32_16x16x64_i8) ----------------
// PHASE 1: in = quantized x (int8 {-1,0,1}) -> int16 acc + slotted atomic max(relu)
// PHASE 2: in = binarized relu(conv1) (int8 {0,1}) -> fp32 out = res + x
// K = 576 = 9 taps x 64 ic; one MFMA K-step = one tap.
template <int PHASE>
__global__ __launch_bounds__(512, 4) void k_conv(
    const float* __restrict__ x,          // original input
    const short* __restrict__ accin,      // phase2: conv1 int16 acc
    const signed char* __restrict__ w8,   // A-fragment-packed weights
    const float* __restrict__ bias,       // b1 (phase1) or b2 (phase2)
    const float* __restrict__ b1v,        // phase2: b1 for dequant of acc
    unsigned* __restrict__ scal,          // [0]=bits(max|x|); slots at +64,+96,..
    short* __restrict__ accout,           // phase1 output
    float* __restrict__ out)              // phase2 output
{
    __shared__ signed char sA[HPX * 64] __attribute__((aligned(16)));   // 39168 B
    __shared__ signed char sW[WELEM]    __attribute__((aligned(16)));   // 36864 B
    __shared__ float redm[8];

    const int tid = threadIdx.x;
    const int n   = blockIdx.z;
    const int oy0 = blockIdx.y * TR;
    const int ox0 = blockIdx.x * TC;

    const float s1 = __uint_as_float(scal[0]) + 1e-8f;

    // ---- stage weights (2304 int4 = 36864 B, already fragment-ordered) ----
    {
        const int4* src = (const int4*)w8;
        int4* dst = (int4*)sW;
        #pragma unroll
        for (int j = 0; j < 4; ++j) dst[tid + j * 512] = src[tid + j * 512];
        if (tid < 256) dst[tid + 2048] = src[tid + 2048];
    }

    // ---- per-phase scales ----
    float inv_s1, sc1_, half_s2_, s2v;
    if (PHASE == 1) {
        inv_s1 = 1.f / s1;
    } else {
        float mx = 0.f;
        #pragma unroll
        for (int i = 0; i < 8; ++i) mx = fmaxf(mx, __uint_as_float(scal[64 + i * 32]));
        s2v = mx + 1e-8f;
        half_s2_ = 0.5f * s2v;
        sc1_ = s1 * (1.f / 3.f);
    }

    // ---- stage + quantize halo tile (18x34 px, 64 ch; one dword=4ic per task) ----
    for (int dw = 0; dw < 16; ++dw) {
        for (int p = tid; p < HPX; p += 512) {
            int r = p / HC, c = p % HC;
            int y  = oy0 - 1 + r;
            int xx = ox0 - 1 + c;
            unsigned pack = 0;
            if (y >= 0 && y < HH && xx >= 0 && xx < WW) {
                if (PHASE == 1) {
                    const float* __restrict__ xp =
                        x + ((size_t)n * CC + dw * 4) * (HH * WW) + y * WW + xx;
                    #pragma unroll
                    for (int j = 0; j < 4; ++j) {
                        float v = xp[(size_t)j * (HH * WW)];
                        int q = (int)rintf(fminf(fmaxf(v * inv_s1, -1.f), 1.f));
                        pack |= (unsigned)(q & 0xff) << (8 * j);
                    }
                } else {
                    const short* __restrict__ ap =
                        accin + ((size_t)n * CC + dw * 4) * (HH * WW) + y * WW + xx;
                    float4 b4 = *(const float4*)(b1v + dw * 4);
                    float bb[4] = {b4.x, b4.y, b4.z, b4.w};
                    #pragma unroll
                    for (int j = 0; j < 4; ++j) {
                        float v = sc1_ * (float)ap[(size_t)j * (HH * WW)] + bb[j];
                        if (v >= half_s2_) pack |= 1u << (8 * j);
                    }
                }
            }
            *(int*)(sA + lds_a(p, dw >> 2) + (dw & 3) * 4) = (int)pack;
        }
    }
    __syncthreads();

    // ---- compute: per wave 2 M-frags (32 oc) x 8 N-frags (4 rows x 2 col-halves) ----
    const int w    = tid >> 6;
    const int lane = tid & 63;
    const int lq   = lane >> 4;
    const int lc   = lane & 15;
    const int mH   = w & 1;               // oc half: 0 -> oc 0..31, 1 -> 32..63
    const int rbase = (w >> 1) * 4;       // 4 output rows per wave

    int32x4 acc0[8] = {};                 // m = mH*2
    int32x4 acc1[8] = {};                 // m = mH*2+1
    #pragma unroll 1
    for (int tap = 0; tap < 9; ++tap) {
        const int ky = tap / 3, kx = tap % 3;
        int32x4 a0 = *(const int32x4*)(sW + (((mH * 2) * 9 + tap) * 64 + lane) * 16);
        int32x4 a1 = *(const int32x4*)(sW + (((mH * 2 + 1) * 9 + tap) * 64 + lane) * 16);
        const int pbase = (rbase + ky) * HC + kx + lc;
        #pragma unroll
        for (int j = 0; j < 8; ++j) {
            int pix = pbase + (j >> 1) * HC + ((j & 1) << 4);
            int32x4 b = *(const int32x4*)(sA + lds_a(pix, lq));
            acc0[j] = __builtin_amdgcn_mfma_i32_16x16x64_i8(a0, b, acc0[j], 0, 0, 0);
            acc1[j] = __builtin_amdgcn_mfma_i32_16x16x64_i8(a1, b, acc1[j], 0, 0, 0);
        }
    }

    // ---- epilogue ----
    const float sc = (PHASE == 1 ? s1 : s2v) * (1.f / 3.f);
    const int ocb = mH * 32 + lq * 4;     // C row = lq*4 + reg within each 16-oc frag
    const size_t PL = (size_t)HH * WW;
    const size_t imgbase = (size_t)n * CC * PL;
    float4 bA = *(const float4*)(bias + ocb);
    float4 bB = *(const float4*)(bias + ocb + 16);
    float bv0[4] = {bA.x, bA.y, bA.z, bA.w};
    float bv1[4] = {bB.x, bB.y, bB.z, bB.w};

    if (PHASE == 1) {
        float m2 = 0.f;
        #pragma unroll
        for (int j = 0; j < 8; ++j) {
            int r  = oy0 + rbase + (j >> 1);
            int cx = ox0 + ((j & 1) << 4) + lc;
            size_t p0 = imgbase + ((size_t)ocb * HH + r) * WW + cx;
            size_t p1 = p0 + 16 * PL;
            #pragma unroll
            for (int g = 0; g < 4; ++g) {
                int v0 = acc0[j][g], v1 = acc1[j][g];
                m2 = fmaxf(m2, sc * (float)v0 + bv0[g]);
                m2 = fmaxf(m2, sc * (float)v1 + bv1[g]);
                accout[p0 + (size_t)g * PL] = (short)v0;
                accout[p1 + (size_t)g * PL] = (short)v1;
            }
        }
        #pragma unroll
        for (int o = 32; o; o >>= 1) m2 = fmaxf(m2, __shfl_down(m2, o, 64));
        if (lane == 0) redm[w] = m2;
        __syncthreads();
        if (tid == 0) {
            float v = redm[0];
            #pragma unroll
            for (int i = 1; i < 8; ++i) v = fmaxf(v, redm[i]);
            int slot = (blockIdx.x + blockIdx.y * 4 + blockIdx.z) & 7;
            atomicMax(&scal[64 + slot * 32], __float_as_uint(v));
        }
    } else {
        #pragma unroll
        for (int j = 0; j < 8; ++j) {
            int r  = oy0 + rbase + (j >> 1);
            int cx = ox0 + ((j & 1) << 4) + lc;
            size_t p0 = imgbase + ((size_t)ocb * HH + r) * WW + cx;
            size_t p1 = p0 + 16 * PL;
            #pragma unroll
            for (int g = 0; g < 4; ++g) {
                out[p0 + (size_t)g * PL] =
                    sc * (float)acc0[j][g] + bv0[g] + x[p0 + (size_t)g * PL];
                out[p1 + (size_t)g * PL] =
                    sc * (float)acc1[j][g] + bv1[g] + x[p1 + (size_t)g * PL];
            }
        }
    }
}

extern "C" void kernel_launch(void* const* d_in, const int* in_sizes, int n_in,
                              void* d_out, int out_size, void* d_ws, size_t ws_size,
                              hipStream_t stream) {
    const float* x  = (const float*)d_in[0];
    const float* w1 = (const float*)d_in[1];
    const float* b1 = (const float*)d_in[2];
    const float* w2 = (const float*)d_in[3];
    const float* b2 = (const float*)d_in[4];
    float* out = (float*)d_out;

    // ws layout
    unsigned*    scal  = (unsigned*)d_ws;                  // [0]=s1; s2 slots at [64+i*32]
    signed char* w8_1  = (signed char*)d_ws + 2048;        // 36864 B
    signed char* w8_2  = w8_1 + WELEM;                     // 36864 B
    short*       acc16 = (short*)((char*)d_ws + 131072);   // 33.5 MB

    hipMemsetAsync(d_ws, 0, 2048, stream);
    k_reduce<<<258, 1024, 0, stream>>>(x, w1, w2, scal, w8_1, w8_2);

    dim3 grid(WW / TC, HH / TR, NB);   // (4, 8, 16)
    k_conv<1><<<grid, 512, 0, stream>>>(x, nullptr, w8_1, b1, nullptr, scal,
                                        acc16, nullptr);
    k_conv<2><<<grid, 512, 0, stream>>>(x, acc16, w8_2, b2, b1, scal,
                                        nullptr, out);
}

// Round 5
// 141.146 us; speedup vs baseline: 4.2331x; 1.0257x over previous
//
#include <hip/hip_runtime.h>
#include <math.h>

// Problem constants (B=16, C=64, H=W=128)
#define NB 16
#define CC 64
#define HH 128
#define WW 128
#define NPIX (NB*CC*HH*WW)       // 16777216
#define WELEM (CC*CC*9)          // 36864

// conv tiling: 16 rows x 32 cols output per block, all 64 oc. halo 18x34.
#define TR 16
#define TC 32
#define HR 18
#define HC 34
#define HPX (HR*HC)              // 612 halo pixels
#define PL  (HH*WW)              // plane stride

typedef __attribute__((ext_vector_type(4))) int   int32x4;
typedef __attribute__((ext_vector_type(4))) short short4_t;

// LDS activation layout: [pix][64B of ic], 16B-chunks XOR-swizzled by (pix>>1)&3.
__device__ __forceinline__ int lds_a(int pix, int q) {
    return pix * 64 + ((q ^ ((pix >> 1) & 3)) << 4);
}

// ---------------- kernel 1: fused global max|x| + DoReFa weight quant ----------------
__global__ __launch_bounds__(1024) void k_reduce(const float* __restrict__ x,
                                                 const float* __restrict__ w1,
                                                 const float* __restrict__ w2,
                                                 unsigned* __restrict__ scal,
                                                 signed char* __restrict__ o1,
                                                 signed char* __restrict__ o2) {
    __shared__ float red[16];
    const int tid = threadIdx.x;
    if (blockIdx.x < 256) {
        const float4* x4 = (const float4*)x;
        const int n4 = NPIX / 4;
        float m = 0.f;
        for (int j = blockIdx.x * 1024 + tid; j < n4; j += 256 * 1024) {
            float4 v = x4[j];
            m = fmaxf(fmaxf(fabsf(v.x), fabsf(v.y)),
                      fmaxf(fmaxf(fabsf(v.z), fabsf(v.w)), m));
        }
        #pragma unroll
        for (int o = 32; o; o >>= 1) m = fmaxf(m, __shfl_down(m, o, 64));
        if ((tid & 63) == 0) red[tid >> 6] = m;
        __syncthreads();
        if (tid == 0) {
            float v = red[0];
            #pragma unroll
            for (int i = 1; i < 16; ++i) v = fmaxf(v, red[i]);
            atomicMax(scal, __float_as_uint(v));
        }
    } else {
        const float* __restrict__ w = (blockIdx.x == 257) ? w2 : w1;
        signed char* __restrict__ w8 = (blockIdx.x == 257) ? o2 : o1;
        float m = 0.f;
        for (int i = tid; i < WELEM; i += 1024) m = fmaxf(m, fabsf(tanhf(w[i])));
        #pragma unroll
        for (int o = 32; o; o >>= 1) m = fmaxf(m, __shfl_down(m, o, 64));
        if ((tid & 63) == 0) red[tid >> 6] = m;
        __syncthreads();
        float mx = 0.f;
        #pragma unroll
        for (int i = 0; i < 16; ++i) mx = fmaxf(mx, red[i]);
        float inv = 1.f / (mx + 1e-8f);
        for (int i = tid; i < WELEM; i += 1024) {
            float wt = tanhf(w[i]) * inv;                 // [-1, 1]
            float r  = rintf((wt + 1.f) * 1.5f);          // 0..3 (round-half-even)
            int oc = i / 576, rem = i % 576, ic = rem / 9, tap = rem % 9;
            // B-fragment: lane = (oc&15) | ((ic>>4)<<4); k-byte = ic&15
            int lane2 = (oc & 15) | ((ic >> 4) << 4);
            w8[(((oc >> 4) * 9 + tap) * 64 + lane2) * 16 + (ic & 15)] =
                (signed char)(int)(2.f * r - 3.f);
        }
    }
}

// ---------------- conv kernels (im2col GEMM on v_mfma_i32_16x16x64_i8) ----------------
// A = activations (M = 16 pixels), B = weights (N = 16 oc) -> C rows are pixels,
// so each lane's 4 C-regs are 4 CONSECUTIVE x positions -> vector epilogue.
template <int PHASE>
__global__ __launch_bounds__(512, 4) void k_conv(
    const float* __restrict__ x,          // original input
    const short* __restrict__ accin,      // phase2: conv1 int16 acc
    const signed char* __restrict__ w8,   // B-fragment-packed weights
    const float* __restrict__ bias,       // b1 (phase1) or b2 (phase2)
    const float* __restrict__ b1v,        // phase2: b1 for dequant of acc
    unsigned* __restrict__ scal,          // [0]=bits(max|x|); slots at +64,+96,..
    short* __restrict__ accout,           // phase1 output
    float* __restrict__ out)              // phase2 output
{
    __shared__ signed char sA[HPX * 64] __attribute__((aligned(16)));   // 39168 B
    __shared__ signed char sW[WELEM]    __attribute__((aligned(16)));   // 36864 B
    __shared__ float redm[8];

    const int tid = threadIdx.x;
    const int n   = blockIdx.z;
    const int oy0 = blockIdx.y * TR;
    const int ox0 = blockIdx.x * TC;

    const float s1 = __uint_as_float(scal[0]) + 1e-8f;

    // ---- stage weights (2304 int4 = 36864 B, already fragment-ordered) ----
    {
        const int4* src = (const int4*)w8;
        int4* dst = (int4*)sW;
        #pragma unroll
        for (int j = 0; j < 4; ++j) dst[tid + j * 512] = src[tid + j * 512];
        if (tid < 256) dst[tid + 2048] = src[tid + 2048];
    }

    // ---- per-phase scales ----
    float inv_s1, sc1_, half_s2_, s2v;
    if (PHASE == 1) {
        inv_s1 = 1.f / s1;
    } else {
        float mx = 0.f;
        #pragma unroll
        for (int i = 0; i < 8; ++i) mx = fmaxf(mx, __uint_as_float(scal[64 + i * 32]));
        s2v = mx + 1e-8f;
        half_s2_ = 0.5f * s2v;
        sc1_ = s1 * (1.f / 3.f);
    }

    // ---- stage + quantize halo tile: tasks = (row r, aligned 4px group cg, ic4) ----
    // 18 rows x 10 groups x 16 ic-quads = 2880 tasks; branch-free clamped loads.
    for (int t = tid; t < HR * 10 * 16; t += 512) {
        const int ic4 = t / (HR * 10);
        const int rcg = t - ic4 * (HR * 10);
        const int r   = rcg / 10;
        const int cg  = rcg - r * 10;
        const int y   = oy0 - 1 + r;
        const int ry  = (y >= 0) & (y < HH);
        const int yc  = min(max(y, 0), HH - 1);
        const int xx0 = ox0 - 4 + cg * 4;                  // multiple of 4
        const int vg  = ry & (xx0 >= 0) & (xx0 < WW);      // group-uniform validity
        const int xc0 = min(max(xx0, 0), WW - 4);

        unsigned pk[4] = {0, 0, 0, 0};
        if (PHASE == 1) {
            const float* __restrict__ xp =
                x + ((size_t)n * CC + ic4 * 4) * PL + yc * WW + xc0;
            #pragma unroll
            for (int j = 0; j < 4; ++j) {
                float4 v = *(const float4*)(xp + (size_t)j * PL);
                float e[4] = {v.x, v.y, v.z, v.w};
                #pragma unroll
                for (int i = 0; i < 4; ++i) {
                    int q = (int)rintf(fminf(fmaxf(e[i] * inv_s1, -1.f), 1.f));
                    pk[i] |= (unsigned)(q & 0xff) << (8 * j);
                }
            }
        } else {
            const short* __restrict__ ap =
                accin + ((size_t)n * CC + ic4 * 4) * PL + yc * WW + xc0;
            float4 b4 = *(const float4*)(b1v + ic4 * 4);
            float bb[4] = {b4.x, b4.y, b4.z, b4.w};
            #pragma unroll
            for (int j = 0; j < 4; ++j) {
                short4_t v = *(const short4_t*)(ap + (size_t)j * PL);
                #pragma unroll
                for (int i = 0; i < 4; ++i) {
                    float e = sc1_ * (float)v[i] + bb[j];
                    if (e >= half_s2_) pk[i] |= 1u << (8 * j);
                }
            }
        }
        const int lo = (ic4 & 3) * 4;
        #pragma unroll
        for (int i = 0; i < 4; ++i) {
            int c = cg * 4 - 3 + i;
            if (c >= 0 && c < HC) {
                int pix = r * HC + c;
                *(int*)(sA + lds_a(pix, ic4 >> 2) + lo) = vg ? (int)pk[i] : 0;
            }
        }
    }
    __syncthreads();

    // ---- compute: per wave, A = 8 pixel-frags, B = 2 oc-frags (32 oc) ----
    const int w     = tid >> 6;
    const int lane  = tid & 63;
    const int lq    = lane >> 4;
    const int lc    = lane & 15;
    const int mH    = w & 1;              // oc half
    const int rbase = (w >> 1) * 4;       // 4 output rows per wave

    int32x4 acc0[8] = {};                 // oc frag mH*2   (oc mH*32 + 0..15)
    int32x4 acc1[8] = {};                 // oc frag mH*2+1 (oc mH*32 + 16..31)
    __builtin_amdgcn_s_setprio(1);
    #pragma unroll 3
    for (int tap = 0; tap < 9; ++tap) {
        const int ky = tap / 3, kx = tap % 3;
        int32x4 b0 = *(const int32x4*)(sW + (((mH * 2) * 9 + tap) * 64 + lane) * 16);
        int32x4 b1 = *(const int32x4*)(sW + (((mH * 2 + 1) * 9 + tap) * 64 + lane) * 16);
        const int pbase = (rbase + ky) * HC + kx + lc;
        #pragma unroll
        for (int j = 0; j < 8; ++j) {
            int pix = pbase + (j >> 1) * HC + ((j & 1) << 4);
            int32x4 a = *(const int32x4*)(sA + lds_a(pix, lq));
            acc0[j] = __builtin_amdgcn_mfma_i32_16x16x64_i8(a, b0, acc0[j], 0, 0, 0);
            acc1[j] = __builtin_amdgcn_mfma_i32_16x16x64_i8(a, b1, acc1[j], 0, 0, 0);
        }
    }
    __builtin_amdgcn_s_setprio(0);

    // ---- epilogue: lane holds 4 consecutive x for oc0/oc1 ----
    const float sc = (PHASE == 1 ? s1 : s2v) * (1.f / 3.f);
    const int oc0 = mH * 32 + lc;
    const int oc1 = oc0 + 16;
    const float bo0 = bias[oc0], bo1 = bias[oc1];
    const size_t imgbase = (size_t)n * CC * PL;

    if (PHASE == 1) {
        float m2 = 0.f;
        #pragma unroll
        for (int j = 0; j < 8; ++j) {
            int yy = oy0 + rbase + (j >> 1);
            int xb = ox0 + ((j & 1) << 4) + lq * 4;
            size_t p0 = imgbase + (size_t)oc0 * PL + yy * WW + xb;
            size_t p1 = imgbase + (size_t)oc1 * PL + yy * WW + xb;
            short4_t s0, s1v;
            #pragma unroll
            for (int g = 0; g < 4; ++g) {
                s0[g]  = (short)acc0[j][g];
                s1v[g] = (short)acc1[j][g];
                m2 = fmaxf(m2, sc * (float)acc0[j][g] + bo0);
                m2 = fmaxf(m2, sc * (float)acc1[j][g] + bo1);
            }
            *(short4_t*)(accout + p0) = s0;
            *(short4_t*)(accout + p1) = s1v;
        }
        #pragma unroll
        for (int o = 32; o; o >>= 1) m2 = fmaxf(m2, __shfl_down(m2, o, 64));
        if (lane == 0) redm[w] = m2;
        __syncthreads();
        if (tid == 0) {
            float v = redm[0];
            #pragma unroll
            for (int i = 1; i < 8; ++i) v = fmaxf(v, redm[i]);
            int slot = (blockIdx.x + blockIdx.y * 4 + blockIdx.z) & 7;
            atomicMax(&scal[64 + slot * 32], __float_as_uint(v));
        }
    } else {
        #pragma unroll
        for (int j = 0; j < 8; ++j) {
            int yy = oy0 + rbase + (j >> 1);
            int xb = ox0 + ((j & 1) << 4) + lq * 4;
            size_t p0 = imgbase + (size_t)oc0 * PL + yy * WW + xb;
            size_t p1 = imgbase + (size_t)oc1 * PL + yy * WW + xb;
            float4 xa = *(const float4*)(x + p0);
            float4 xb4 = *(const float4*)(x + p1);
            float4 r0, r1;
            r0.x = sc * (float)acc0[j][0] + bo0 + xa.x;
            r0.y = sc * (float)acc0[j][1] + bo0 + xa.y;
            r0.z = sc * (float)acc0[j][2] + bo0 + xa.z;
            r0.w = sc * (float)acc0[j][3] + bo0 + xa.w;
            r1.x = sc * (float)acc1[j][0] + bo1 + xb4.x;
            r1.y = sc * (float)acc1[j][1] + bo1 + xb4.y;
            r1.z = sc * (float)acc1[j][2] + bo1 + xb4.z;
            r1.w = sc * (float)acc1[j][3] + bo1 + xb4.w;
            *(float4*)(out + p0) = r0;
            *(float4*)(out + p1) = r1;
        }
    }
}

extern "C" void kernel_launch(void* const* d_in, const int* in_sizes, int n_in,
                              void* d_out, int out_size, void* d_ws, size_t ws_size,
                              hipStream_t stream) {
    const float* x  = (const float*)d_in[0];
    const float* w1 = (const float*)d_in[1];
    const float* b1 = (const float*)d_in[2];
    const float* w2 = (const float*)d_in[3];
    const float* b2 = (const float*)d_in[4];
    float* out = (float*)d_out;

    // ws layout
    unsigned*    scal  = (unsigned*)d_ws;                  // [0]=s1; s2 slots at [64+i*32]
    signed char* w8_1  = (signed char*)d_ws + 2048;        // 36864 B
    signed char* w8_2  = w8_1 + WELEM;                     // 36864 B
    short*       acc16 = (short*)((char*)d_ws + 131072);   // 33.5 MB

    hipMemsetAsync(d_ws, 0, 2048, stream);
    k_reduce<<<258, 1024, 0, stream>>>(x, w1, w2, scal, w8_1, w8_2);

    dim3 grid(WW / TC, HH / TR, NB);   // (4, 8, 16)
    k_conv<1><<<grid, 512, 0, stream>>>(x, nullptr, w8_1, b1, nullptr, scal,
                                        acc16, nullptr);
    k_conv<2><<<grid, 512, 0, stream>>>(x, acc16, w8_2, b2, b1, scal,
                                        nullptr, out);
}

// Round 6
// 127.516 us; speedup vs baseline: 4.6856x; 1.1069x over previous
//
#include <hip/hip_runtime.h>
#include <math.h>

// Problem constants (B=16, C=64, H=W=128)
#define NB 16
#define CC 64
#define HH 128
#define WW 128
#define NPIX (NB*CC*HH*WW)       // 16777216
#define WELEM (CC*CC*9)          // 36864

// conv tiling: 16 rows x 32 cols output per block, all 64 oc. halo 18x34.
#define TR 16
#define TC 32
#define HR 18
#define HC 34
#define HPX (HR*HC)              // 612 halo pixels
#define PL  (HH*WW)              // plane stride

// padded quantized-x tensor: [n][132 rows][130 cols][64 ic] int8
// padded row r <-> image y = r-1 ; padded col c <-> image x = c-1
#define PYY 132
#define PXX 130
#define XQIMG (PYY*PXX*64)       // 1098240 B per image
#define XQTOT (NB*XQIMG)         // 17571840 B

typedef __attribute__((ext_vector_type(4))) int   int32x4;
typedef __attribute__((ext_vector_type(4))) short short4_t;

// LDS activation layout: [pix][64B of ic], 16B-chunks XOR-swizzled by (pix>>1)&3.
__device__ __forceinline__ int lds_a(int pix, int q) {
    return pix * 64 + ((q ^ ((pix >> 1) & 3)) << 4);
}

// ---------------- kernel 1: fused global max|x| + DoReFa weight quant ----------------
__global__ __launch_bounds__(1024) void k_reduce(const float* __restrict__ x,
                                                 const float* __restrict__ w1,
                                                 const float* __restrict__ w2,
                                                 unsigned* __restrict__ scal,
                                                 signed char* __restrict__ o1,
                                                 signed char* __restrict__ o2) {
    __shared__ float red[16];
    const int tid = threadIdx.x;
    if (blockIdx.x < 256) {
        const float4* x4 = (const float4*)x;
        const int n4 = NPIX / 4;
        float m = 0.f;
        for (int j = blockIdx.x * 1024 + tid; j < n4; j += 256 * 1024) {
            float4 v = x4[j];
            m = fmaxf(fmaxf(fabsf(v.x), fabsf(v.y)),
                      fmaxf(fmaxf(fabsf(v.z), fabsf(v.w)), m));
        }
        #pragma unroll
        for (int o = 32; o; o >>= 1) m = fmaxf(m, __shfl_down(m, o, 64));
        if ((tid & 63) == 0) red[tid >> 6] = m;
        __syncthreads();
        if (tid == 0) {
            float v = red[0];
            #pragma unroll
            for (int i = 1; i < 16; ++i) v = fmaxf(v, red[i]);
            atomicMax(scal, __float_as_uint(v));
        }
    } else {
        const float* __restrict__ w = (blockIdx.x == 257) ? w2 : w1;
        signed char* __restrict__ w8 = (blockIdx.x == 257) ? o2 : o1;
        float m = 0.f;
        for (int i = tid; i < WELEM; i += 1024) m = fmaxf(m, fabsf(tanhf(w[i])));
        #pragma unroll
        for (int o = 32; o; o >>= 1) m = fmaxf(m, __shfl_down(m, o, 64));
        if ((tid & 63) == 0) red[tid >> 6] = m;
        __syncthreads();
        float mx = 0.f;
        #pragma unroll
        for (int i = 0; i < 16; ++i) mx = fmaxf(mx, red[i]);
        float inv = 1.f / (mx + 1e-8f);
        for (int i = tid; i < WELEM; i += 1024) {
            float wt = tanhf(w[i]) * inv;                 // [-1, 1]
            float r  = rintf((wt + 1.f) * 1.5f);          // 0..3 (round-half-even)
            int oc = i / 576, rem = i % 576, ic = rem / 9, tap = rem % 9;
            // B-fragment: lane = (oc&15) | ((ic>>4)<<4); k-byte = ic&15
            int lane2 = (oc & 15) | ((ic >> 4) << 4);
            w8[(((oc >> 4) * 9 + tap) * 64 + lane2) * 16 + (ic & 15)] =
                (signed char)(int)(2.f * r - 3.f);
        }
    }
}

// ---------------- kernel 1b: quantize x -> padded pixel-major int8 ----------------
// block: (seg s in {0,1}, image row y, image n); 256 threads; 64 px x 64 ic.
__global__ __launch_bounds__(256) void k_quantx(const float* __restrict__ x,
                                                const unsigned* __restrict__ scal,
                                                signed char* __restrict__ xq) {
    __shared__ signed char ldsA[64 * 68];   // [ic][px], pitch 68 breaks conflicts
    __shared__ int ldsB[64 * 16];           // [px][16 dwords] = final layout
    const int tid = threadIdx.x;
    const int n = blockIdx.z, y = blockIdx.y, s = blockIdx.x;
    const float inv_s1 = 1.f / (__uint_as_float(scal[0]) + 1e-8f);

    // phase A: thread (ic, g): quantize 16 px from channel plane ic
    {
        const int ic = tid >> 2, g = tid & 3;
        const float* __restrict__ src =
            x + (((size_t)n * CC + ic) * HH + y) * WW + s * 64 + g * 16;
        unsigned dw[4];
        #pragma unroll
        for (int q = 0; q < 4; ++q) {
            float4 v = *(const float4*)(src + q * 4);
            float e[4] = {v.x, v.y, v.z, v.w};
            unsigned d = 0;
            #pragma unroll
            for (int j = 0; j < 4; ++j) {
                int qq = (int)rintf(fminf(fmaxf(e[j] * inv_s1, -1.f), 1.f));
                d |= (unsigned)(qq & 255) << (8 * j);
            }
            dw[q] = d;
        }
        *(int4*)(ldsA + ic * 68 + g * 16) = *(const int4*)dw;
    }
    __syncthreads();
    // phase B: transpose to [px][ic] packed dwords
    #pragma unroll
    for (int i = 0; i < 4; ++i) {
        int idx = tid + i * 256;
        int d = idx & 15, p = idx >> 4;
        const signed char* a = ldsA + (d * 4) * 68 + p;
        unsigned b0 = (unsigned char)a[0];
        unsigned b1 = (unsigned char)a[68];
        unsigned b2 = (unsigned char)a[136];
        unsigned b3 = (unsigned char)a[204];
        ldsB[p * 16 + d] = (int)(b0 | (b1 << 8) | (b2 << 16) | (b3 << 24));
    }
    __syncthreads();
    // coalesced copy to padded global (interior only; borders stay memset-0)
    signed char* dst = xq + ((size_t)n * PYY + (y + 1)) * (PXX * 64)
                          + (size_t)(1 + s * 64) * 64;
    ((int4*)dst)[tid] = ((const int4*)ldsB)[tid];
}

// ---------------- conv1: im2col GEMM on v_mfma_i32_16x16x64_i8 ----------------
// A = activations (M = 16 pixels), B = weights (N = 16 oc).
__global__ __launch_bounds__(512, 4) void k_conv1(
    const signed char* __restrict__ xq,   // padded pixel-major int8
    const signed char* __restrict__ w8,   // B-fragment-packed weights
    const float* __restrict__ bias,       // b1
    unsigned* __restrict__ scal,          // [0]=s1 bits; s2 slots at 64+i*32
    short* __restrict__ accout)
{
    __shared__ signed char sA[640 * 64] __attribute__((aligned(16)));   // 40960 B
    __shared__ signed char sW[WELEM]    __attribute__((aligned(16)));   // 36864 B
    __shared__ float redm[8];

    const int tid = threadIdx.x;
    const int n   = blockIdx.z;
    const int oy0 = blockIdx.y * TR;
    const int ox0 = blockIdx.x * TC;
    const float s1 = __uint_as_float(scal[0]) + 1e-8f;

    // stage weights (already fragment-ordered)
    {
        const int4* src = (const int4*)w8;
        int4* dst = (int4*)sW;
        #pragma unroll
        for (int j = 0; j < 4; ++j) dst[tid + j * 512] = src[tid + j * 512];
        if (tid < 256) dst[tid + 2048] = src[tid + 2048];
    }

    // stage activations: pure byte-copy from padded xq, swizzled ds_write_b128
    {
        const signed char* __restrict__ xqn = xq + (size_t)n * XQIMG;
        #pragma unroll
        for (int k = 0; k < 5; ++k) {
            int cid = tid + k * 512;          // 0..2559 (640 px x 4 chunks)
            int p = cid >> 2, c = cid & 3;
            int py = p / HC, px = p - py * HC;
            const int4 v = *(const int4*)(xqn
                + ((size_t)((oy0 + py) * PXX + ox0 + px) << 6) + (c << 4));
            *(int4*)(sA + lds_a(p, c)) = v;
        }
    }
    __syncthreads();

    // compute: per wave, A = 8 pixel-frags, B = 2 oc-frags (32 oc)
    const int w     = tid >> 6;
    const int lane  = tid & 63;
    const int lq    = lane >> 4;
    const int lc    = lane & 15;
    const int mH    = w & 1;
    const int rbase = (w >> 1) * 4;

    int32x4 acc0[8] = {};
    int32x4 acc1[8] = {};
    __builtin_amdgcn_s_setprio(1);
    #pragma unroll 3
    for (int tap = 0; tap < 9; ++tap) {
        const int ky = tap / 3, kx = tap % 3;
        int32x4 b0 = *(const int32x4*)(sW + (((mH * 2) * 9 + tap) * 64 + lane) * 16);
        int32x4 b1 = *(const int32x4*)(sW + (((mH * 2 + 1) * 9 + tap) * 64 + lane) * 16);
        const int pbase = (rbase + ky) * HC + kx + lc;
        #pragma unroll
        for (int j = 0; j < 8; ++j) {
            int pix = pbase + (j >> 1) * HC + ((j & 1) << 4);
            int32x4 a = *(const int32x4*)(sA + lds_a(pix, lq));
            acc0[j] = __builtin_amdgcn_mfma_i32_16x16x64_i8(a, b0, acc0[j], 0, 0, 0);
            acc1[j] = __builtin_amdgcn_mfma_i32_16x16x64_i8(a, b1, acc1[j], 0, 0, 0);
        }
    }
    __builtin_amdgcn_s_setprio(0);

    // epilogue: int16 acc store + slotted atomic relu-max
    const float sc = s1 * (1.f / 3.f);
    const int oc0 = mH * 32 + lc;
    const int oc1 = oc0 + 16;
    const float bo0 = bias[oc0], bo1 = bias[oc1];
    const size_t imgbase = (size_t)n * CC * PL;

    float m2 = 0.f;
    #pragma unroll
    for (int j = 0; j < 8; ++j) {
        int yy = oy0 + rbase + (j >> 1);
        int xb = ox0 + ((j & 1) << 4) + lq * 4;
        size_t p0 = imgbase + (size_t)oc0 * PL + yy * WW + xb;
        size_t p1 = imgbase + (size_t)oc1 * PL + yy * WW + xb;
        short4_t s0, s1v;
        #pragma unroll
        for (int g = 0; g < 4; ++g) {
            s0[g]  = (short)acc0[j][g];
            s1v[g] = (short)acc1[j][g];
            m2 = fmaxf(m2, sc * (float)acc0[j][g] + bo0);
            m2 = fmaxf(m2, sc * (float)acc1[j][g] + bo1);
        }
        *(short4_t*)(accout + p0) = s0;
        *(short4_t*)(accout + p1) = s1v;
    }
    #pragma unroll
    for (int o = 32; o; o >>= 1) m2 = fmaxf(m2, __shfl_down(m2, o, 64));
    if (lane == 0) redm[w] = m2;
    __syncthreads();
    if (tid == 0) {
        float v = redm[0];
        #pragma unroll
        for (int i = 1; i < 8; ++i) v = fmaxf(v, redm[i]);
        int slot = (blockIdx.x + blockIdx.y * 4 + blockIdx.z) & 7;
        atomicMax(&scal[64 + slot * 32], __float_as_uint(v));
    }
}

// ---------------- conv2: binarize-stage + MFMA + residual epilogue ----------------
__global__ __launch_bounds__(512, 4) void k_conv2(
    const float* __restrict__ x,
    const short* __restrict__ accin,
    const signed char* __restrict__ w8,
    const float* __restrict__ bias,       // b2
    const float* __restrict__ b1v,        // b1 (dequant of acc)
    const unsigned* __restrict__ scal,
    float* __restrict__ out)
{
    __shared__ signed char sA[640 * 64] __attribute__((aligned(16)));
    __shared__ signed char sW[WELEM]    __attribute__((aligned(16)));

    const int tid = threadIdx.x;
    const int n   = blockIdx.z;
    const int oy0 = blockIdx.y * TR;
    const int ox0 = blockIdx.x * TC;

    const float s1 = __uint_as_float(scal[0]) + 1e-8f;

    {
        const int4* src = (const int4*)w8;
        int4* dst = (int4*)sW;
        #pragma unroll
        for (int j = 0; j < 4; ++j) dst[tid + j * 512] = src[tid + j * 512];
        if (tid < 256) dst[tid + 2048] = src[tid + 2048];
    }

    float mx = 0.f;
    #pragma unroll
    for (int i = 0; i < 8; ++i) mx = fmaxf(mx, __uint_as_float(scal[64 + i * 32]));
    const float s2v = mx + 1e-8f;
    const float half_s2 = 0.5f * s2v;
    const float sc1 = s1 * (1.f / 3.f);

    // stage + binarize halo: tasks = (row r, aligned 4px group cg, ic4)
    for (int t = tid; t < HR * 10 * 16; t += 512) {
        const int ic4 = t / (HR * 10);
        const int rcg = t - ic4 * (HR * 10);
        const int r   = rcg / 10;
        const int cg  = rcg - r * 10;
        const int y   = oy0 - 1 + r;
        const int ry  = (y >= 0) & (y < HH);
        const int yc  = min(max(y, 0), HH - 1);
        const int xx0 = ox0 - 4 + cg * 4;
        const int vg  = ry & (xx0 >= 0) & (xx0 < WW);
        const int xc0 = min(max(xx0, 0), WW - 4);

        unsigned pk[4] = {0, 0, 0, 0};
        const short* __restrict__ ap =
            accin + ((size_t)n * CC + ic4 * 4) * PL + yc * WW + xc0;
        float4 b4 = *(const float4*)(b1v + ic4 * 4);
        float bb[4] = {b4.x, b4.y, b4.z, b4.w};
        #pragma unroll
        for (int j = 0; j < 4; ++j) {
            short4_t v = *(const short4_t*)(ap + (size_t)j * PL);
            #pragma unroll
            for (int i = 0; i < 4; ++i) {
                float e = sc1 * (float)v[i] + bb[j];
                if (e >= half_s2) pk[i] |= 1u << (8 * j);
            }
        }
        const int lo = (ic4 & 3) * 4;
        #pragma unroll
        for (int i = 0; i < 4; ++i) {
            int c = cg * 4 - 3 + i;
            if (c >= 0 && c < HC) {
                int pix = r * HC + c;
                *(int*)(sA + lds_a(pix, ic4 >> 2) + lo) = vg ? (int)pk[i] : 0;
            }
        }
    }
    __syncthreads();

    const int w     = tid >> 6;
    const int lane  = tid & 63;
    const int lq    = lane >> 4;
    const int lc    = lane & 15;
    const int mH    = w & 1;
    const int rbase = (w >> 1) * 4;

    int32x4 acc0[8] = {};
    int32x4 acc1[8] = {};
    __builtin_amdgcn_s_setprio(1);
    #pragma unroll 3
    for (int tap = 0; tap < 9; ++tap) {
        const int ky = tap / 3, kx = tap % 3;
        int32x4 b0 = *(const int32x4*)(sW + (((mH * 2) * 9 + tap) * 64 + lane) * 16);
        int32x4 b1 = *(const int32x4*)(sW + (((mH * 2 + 1) * 9 + tap) * 64 + lane) * 16);
        const int pbase = (rbase + ky) * HC + kx + lc;
        #pragma unroll
        for (int j = 0; j < 8; ++j) {
            int pix = pbase + (j >> 1) * HC + ((j & 1) << 4);
            int32x4 a = *(const int32x4*)(sA + lds_a(pix, lq));
            acc0[j] = __builtin_amdgcn_mfma_i32_16x16x64_i8(a, b0, acc0[j], 0, 0, 0);
            acc1[j] = __builtin_amdgcn_mfma_i32_16x16x64_i8(a, b1, acc1[j], 0, 0, 0);
        }
    }
    __builtin_amdgcn_s_setprio(0);

    const float sc = s2v * (1.f / 3.f);
    const int oc0 = mH * 32 + lc;
    const int oc1 = oc0 + 16;
    const float bo0 = bias[oc0], bo1 = bias[oc1];
    const size_t imgbase = (size_t)n * CC * PL;

    #pragma unroll
    for (int j = 0; j < 8; ++j) {
        int yy = oy0 + rbase + (j >> 1);
        int xb = ox0 + ((j & 1) << 4) + lq * 4;
        size_t p0 = imgbase + (size_t)oc0 * PL + yy * WW + xb;
        size_t p1 = imgbase + (size_t)oc1 * PL + yy * WW + xb;
        float4 xa  = *(const float4*)(x + p0);
        float4 xb4 = *(const float4*)(x + p1);
        float4 r0, r1;
        r0.x = sc * (float)acc0[j][0] + bo0 + xa.x;
        r0.y = sc * (float)acc0[j][1] + bo0 + xa.y;
        r0.z = sc * (float)acc0[j][2] + bo0 + xa.z;
        r0.w = sc * (float)acc0[j][3] + bo0 + xa.w;
        r1.x = sc * (float)acc1[j][0] + bo1 + xb4.x;
        r1.y = sc * (float)acc1[j][1] + bo1 + xb4.y;
        r1.z = sc * (float)acc1[j][2] + bo1 + xb4.z;
        r1.w = sc * (float)acc1[j][3] + bo1 + xb4.w;
        *(float4*)(out + p0) = r0;
        *(float4*)(out + p1) = r1;
    }
}

extern "C" void kernel_launch(void* const* d_in, const int* in_sizes, int n_in,
                              void* d_out, int out_size, void* d_ws, size_t ws_size,
                              hipStream_t stream) {
    const float* x  = (const float*)d_in[0];
    const float* w1 = (const float*)d_in[1];
    const float* b1 = (const float*)d_in[2];
    const float* w2 = (const float*)d_in[3];
    const float* b2 = (const float*)d_in[4];
    float* out = (float*)d_out;

    // ws layout
    unsigned*    scal  = (unsigned*)d_ws;                  // [0]=s1; s2 slots at [64+i*32]
    signed char* w8_1  = (signed char*)d_ws + 2048;        // 36864 B
    signed char* w8_2  = w8_1 + WELEM;                     // 36864 B
    short*       acc16 = (short*)((char*)d_ws + 131072);   // 33.5 MB
    // xq lives in d_out's scratch space: written by k_quantx, read only by
    // k_conv1, fully overwritten by k_conv2's final output.
    signed char* xq    = (signed char*)d_out;

    hipMemsetAsync(d_ws, 0, 2048, stream);
    hipMemsetAsync(d_out, 0, XQTOT, stream);   // zero padded borders of xq

    k_reduce<<<258, 1024, 0, stream>>>(x, w1, w2, scal, w8_1, w8_2);
    k_quantx<<<dim3(2, HH, NB), 256, 0, stream>>>(x, scal, xq);

    dim3 grid(WW / TC, HH / TR, NB);   // (4, 8, 16)
    k_conv1<<<grid, 512, 0, stream>>>(xq, w8_1, b1, scal, acc16);
    k_conv2<<<grid, 512, 0, stream>>>(x, acc16, w8_2, b2, b1, scal, out);
}